// Round 2
// baseline (671.416 us; speedup 1.0000x reference)
//
#include <hip/hip_runtime.h>
#include <math.h>

// AxialChannelAttention on MI355X, fp32.
// Decomposition:
//   axial = U[b,r,w] + V[b,r,h]  (separable pooling through linear conv1)
//   lrelu(s) = 0.505*s + 0.495*|s|
//   g_avg+g_max = PS[b,c,w] + QS[b,c,h] + 0.495 * sum_r w2[c,r]*m[b,r,h,w]
//   m = |U_a+V_a| + |U_m+V_m|   (single per-pixel matvec for BOTH branches)
// K1: pool (read x once).  K2a: w1 GEMMs -> U.  K2b: w2 GEMMs -> PS/QS.
// K3: per-(b,h) block: build m[64][128] in LDS, GEMM w2[256x64]*m -> fused
//     sigmoid epilogue, out = x*(1+scale).

#define B_  16
#define C_  256
#define CR_ 64
#define H_  128
#define W_  128

constexpr size_t SSTRIDE  = (size_t)B_ * C_ * W_;   // 524288 floats per stat array
constexpr size_t USTRIDE  = (size_t)B_ * CR_ * W_;  // 131072 floats per U array
constexpr size_t PQSTRIDE = (size_t)B_ * C_ * W_;   // 524288 floats per PS/QS

// ---------------- Kernel 1: axial pooling (sum+max over H and over W) ---------
// One block per (b,c) plane. Lanes own 2 w-columns (float2 loads, coalesced);
// row stats via 64-lane butterfly shuffle; column partials combined via LDS.
__global__ __launch_bounds__(256) void k1_pool(const float* __restrict__ x,
                                               float* __restrict__ S) {
    const int c = blockIdx.x, b = blockIdx.y;
    const int tid  = threadIdx.x;
    const int wv   = tid >> 6;     // wave 0..3, handles rows wv*32..wv*32+31
    const int lane = tid & 63;
    const float* xp = x + (size_t)(b * C_ + c) * (H_ * W_);

    __shared__ float rs_l[H_], rm_l[H_];
    __shared__ float cs_l[4][W_], cm_l[4][W_];

    float csx = 0.f, csy = 0.f;
    float cmx = -3.402823466e38f, cmy = -3.402823466e38f;

    for (int j = 0; j < 32; ++j) {
        const int h = wv * 32 + j;
        const float2 v = *reinterpret_cast<const float2*>(xp + h * W_ + lane * 2);
        csx += v.x; csy += v.y;
        cmx = fmaxf(cmx, v.x); cmy = fmaxf(cmy, v.y);
        float rs = v.x + v.y;
        float rm = fmaxf(v.x, v.y);
#pragma unroll
        for (int msk = 1; msk < 64; msk <<= 1) {
            rs += __shfl_xor(rs, msk);
            rm = fmaxf(rm, __shfl_xor(rm, msk));
        }
        if (lane == 0) { rs_l[h] = rs; rm_l[h] = rm; }
    }
    cs_l[wv][2 * lane]     = csx;  cs_l[wv][2 * lane + 1] = csy;
    cm_l[wv][2 * lane]     = cmx;  cm_l[wv][2 * lane + 1] = cmy;
    __syncthreads();

    if (tid < 128) {
        const float ssum = cs_l[0][tid] + cs_l[1][tid] + cs_l[2][tid] + cs_l[3][tid];
        const float smax = fmaxf(fmaxf(cm_l[0][tid], cm_l[1][tid]),
                                 fmaxf(cm_l[2][tid], cm_l[3][tid]));
        const size_t o = (size_t)(b * C_ + c) * W_ + tid;
        S[0 * SSTRIDE + o] = ssum * (1.0f / 128.0f);  // avg_h[b,c,w]
        S[1 * SSTRIDE + o] = smax;                    // max_h[b,c,w]
        S[2 * SSTRIDE + o] = rs_l[tid] * (1.0f / 128.0f); // avg_w[b,c,h]
        S[3 * SSTRIDE + o] = rm_l[tid];               // max_w[b,c,h]
    }
}

// ---------------- Kernel 2a: U[src][b][r][t] = sum_c w1[r,c] * S[src][b][c][t]
__global__ __launch_bounds__(128) void k2a_u(const float* __restrict__ S,
                                             const float* __restrict__ w1,
                                             float* __restrict__ U) {
    const int t   = threadIdx.x;   // 0..127 (w or h)
    const int rq  = blockIdx.x;    // 0..7  -> 8 r's per block
    const int src = blockIdx.y;    // 0..3
    const int b   = blockIdx.z;
    const float* in = S + ((size_t)(src * B_ + b) * C_) * W_;

    float acc[8];
#pragma unroll
    for (int i = 0; i < 8; ++i) acc[i] = 0.f;

#pragma unroll 4
    for (int c = 0; c < C_; ++c) {
        const float xv = in[c * W_ + t];
#pragma unroll
        for (int i = 0; i < 8; ++i)
            acc[i] = fmaf(w1[(rq * 8 + i) * C_ + c], xv, acc[i]);  // uniform -> s_load
    }
    float* o = U + ((size_t)(src * B_ + b) * CR_ + rq * 8) * W_;
#pragma unroll
    for (int i = 0; i < 8; ++i) o[i * W_ + t] = acc[i];
}

// ---------------- Kernel 2b: PS/QS (linear part of lrelu through conv2) ------
// PS[b,c,w] = 0.505 * sum_r w2[c,r]*(U_a[b,r,w]+U_m[b,r,w]);  QS analog with V.
__global__ __launch_bounds__(128) void k2b_pq(const float* __restrict__ U,
                                              const float* __restrict__ w2,
                                              float* __restrict__ PQ) {
    const int t  = threadIdx.x;  // w or h
    const int cq = blockIdx.x;   // 0..15 -> 16 c's per block
    const int pq = blockIdx.y;   // 0 = PS (from U_a,U_m), 1 = QS (from V_a,V_m)
    const int b  = blockIdx.z;
    const float* u0 = U + ((size_t)((pq * 2 + 0) * B_ + b) * CR_) * W_;
    const float* u1 = U + ((size_t)((pq * 2 + 1) * B_ + b) * CR_) * W_;

    float acc[16];
#pragma unroll
    for (int i = 0; i < 16; ++i) acc[i] = 0.f;

#pragma unroll 4
    for (int r = 0; r < CR_; ++r) {
        const float sv = u0[r * W_ + t] + u1[r * W_ + t];
#pragma unroll
        for (int i = 0; i < 16; ++i)
            acc[i] = fmaf(w2[(cq * 16 + i) * CR_ + r], sv, acc[i]);  // uniform -> s_load
    }
    float* o = PQ + ((size_t)(pq * B_ + b) * C_ + cq * 16) * W_;
#pragma unroll
    for (int i = 0; i < 16; ++i) o[i * W_ + t] = 0.505f * acc[i];
}

// ---------------- Kernel 3: fused abs-matvec + sigmoid + scale ---------------
// One block per (b,h). m[64][128] in LDS (conflict-free: lanes stride-1 in w).
// Each thread: fixed w, 128 c's in 8 chunks of 16 accumulators.
__global__ __launch_bounds__(256) void k3_gate(const float* __restrict__ x,
                                               const float* __restrict__ U,
                                               const float* __restrict__ PQ,
                                               const float* __restrict__ w2,
                                               float* __restrict__ out) {
    const int h = blockIdx.x, b = blockIdx.y;
    const int tid = threadIdx.x;

    __shared__ float sm[CR_][W_];  // 32 KiB

    const float* Ua = U + (size_t)(0 * B_ + b) * CR_ * W_;
    const float* Um = U + (size_t)(1 * B_ + b) * CR_ * W_;
    const float* Va = U + (size_t)(2 * B_ + b) * CR_ * W_;
    const float* Vm = U + (size_t)(3 * B_ + b) * CR_ * W_;

    for (int idx = tid; idx < CR_ * W_; idx += 256) {
        const int r = idx >> 7, w = idx & 127;
        const float va = Va[r * W_ + h];   // wave-uniform
        const float vm = Vm[r * W_ + h];
        sm[r][w] = fabsf(Ua[r * W_ + w] + va) + fabsf(Um[r * W_ + w] + vm);
    }
    __syncthreads();

    const int w  = tid & 127;
    const int cg = __builtin_amdgcn_readfirstlane(tid >> 7);  // 0 or 1, SGPR
    const float* PQ0 = PQ + (size_t)b * C_ * W_;              // PS[b][c][w]
    const float* PQ1 = PQ + PQSTRIDE + (size_t)b * C_ * W_;   // QS[b][c][h]

    for (int oc = 0; oc < 8; ++oc) {
        const int cbase = cg * 128 + oc * 16;
        float acc[16];
#pragma unroll
        for (int i = 0; i < 16; ++i) acc[i] = 0.f;

#pragma unroll 4
        for (int r = 0; r < CR_; ++r) {
            const float mv = sm[r][w];
#pragma unroll
            for (int i = 0; i < 16; ++i)
                acc[i] = fmaf(w2[(cbase + i) * CR_ + r], mv, acc[i]);  // uniform -> s_load
        }
#pragma unroll
        for (int i = 0; i < 16; ++i) {
            const int c = cbase + i;
            const float z = PQ0[(size_t)c * W_ + w] + PQ1[(size_t)c * W_ + h]
                            + 0.495f * acc[i];
            const float sg = 1.0f / (1.0f + __expf(-z));  // sigmoid(z)
            const size_t xo = (((size_t)(b * C_ + c)) * H_ + h) * W_ + w;
            out[xo] = x[xo] * (1.0f + sg);
        }
    }
}

extern "C" void kernel_launch(void* const* d_in, const int* in_sizes, int n_in,
                              void* d_out, int out_size, void* d_ws, size_t ws_size,
                              hipStream_t stream) {
    (void)in_sizes; (void)n_in; (void)out_size; (void)ws_size;
    const float* x  = (const float*)d_in[0];
    const float* w1 = (const float*)d_in[1];
    const float* w2 = (const float*)d_in[2];
    float* out = (float*)d_out;

    float* S  = (float*)d_ws;              // 4 * 524288 floats
    float* U  = S + 4 * SSTRIDE;           // 4 * 131072 floats
    float* PQ = U + 4 * USTRIDE;           // 2 * 524288 floats
    // total workspace: 3,670,016 floats = 14 MB

    k1_pool<<<dim3(C_, B_), 256, 0, stream>>>(x, S);
    k2a_u  <<<dim3(8, 4, B_), 128, 0, stream>>>(S, w1, U);
    k2b_pq <<<dim3(16, 2, B_), 128, 0, stream>>>(U, w2, PQ);
    k3_gate<<<dim3(H_, B_), 256, 0, stream>>>(x, U, PQ, w2, out);
}